// Round 8
// baseline (142.015 us; speedup 1.0000x reference)
//
#include <hip/hip_runtime.h>
#include <string.h>

// Problem constants (from reference setup_inputs)
#define Hh   256
#define SIXH 1536
#define Bb_  32
#define Ll_  512
#define BL_  16384   // B*L
#define Mm_  1024
#define N1_  1024    // 4H
#define K1_  1536    // 6H
#define K2_  1024
#define N2_  256

typedef __attribute__((ext_vector_type(8))) short bf16x8;
typedef __attribute__((ext_vector_type(4))) float f32x4;

__device__ inline float bf2f(unsigned short u){ unsigned x=(unsigned)u<<16; float f; memcpy(&f,&x,4); return f; }
__device__ inline unsigned short f2bf(float f){ unsigned x; memcpy(&x,&f,4); x = x + 0x7FFFu + ((x>>16)&1u); return (unsigned short)(x>>16); }

#define GL16(gp, lp) __builtin_amdgcn_global_load_lds( \
    (const __attribute__((address_space(1))) void*)(gp), \
    (__attribute__((address_space(3))) void*)(lp), 16, 0, 0)

// ---------------------------------------------------------------------------
// Mask dtype detection: flag 0 = int32, 1 = byte(bool), 2 = float32.
__global__ void detect_mask_kernel(const unsigned int* __restrict__ m, int* __restrict__ flag){
  int t = threadIdx.x;
  bool gt1=false, isf=false;
  for (int i=t;i<4096;i+=256){ unsigned v=m[i]; if(v>1u) gt1=true; if(v==0x3F800000u) isf=true; }
  unsigned long long bg = __ballot(gt1), bf = __ballot(isf);
  __shared__ unsigned long long s1[4], s2[4];
  int w = t>>6;
  if ((t&63)==0){ s1[w]=bg; s2[w]=bf; }
  __syncthreads();
  if (t==0){
    bool g = (s1[0]|s1[1]|s1[2]|s1[3])!=0ull;
    bool f = (s2[0]|s2[1]|s2[2]|s2[3])!=0ull;
    *flag = g ? (f?2:1) : 0;
  }
}

// ---------------------------------------------------------------------------
// Tiled transpose + fp32->bf16 convert: W [K][N] f32  ->  Wt [N][K] bf16.
__global__ __launch_bounds__(256) void transpose_conv_kernel(
  const float* __restrict__ W, unsigned short* __restrict__ Wt, int K, int N)
{
  __shared__ float t[32][33];
  int ntx = N >> 5;
  int bx = blockIdx.x % ntx;
  int by = blockIdx.x / ntx;
  int tx = threadIdx.x & 31, ty = threadIdx.x >> 5;
  #pragma unroll
  for (int i=0;i<32;i+=8)
    t[ty+i][tx] = W[(size_t)(by*32+ty+i)*N + bx*32+tx];
  __syncthreads();
  #pragma unroll
  for (int i=0;i<32;i+=8)
    Wt[(size_t)(bx*32+ty+i)*K + by*32+tx] = f2bf(t[tx][ty+i]);
}

// ---------------------------------------------------------------------------
// Gather 6 embedding segments + LayerNorm(1536) -> xn bf16 [16384][1536]
__global__ __launch_bounds__(256) void gather_ln_kernel(
  const int* __restrict__ tok, const int* __restrict__ post,
  const int* __restrict__ auth, const int* __restrict__ act,
  const int* __restrict__ tg,  const int* __restrict__ gidp,
  const float* __restrict__ token_emb, const float* __restrict__ time_emb,
  const float* __restrict__ group_emb,
  const float* __restrict__ ln_g, const float* __restrict__ ln_b,
  unsigned short* __restrict__ xn)
{
  int row = blockIdx.x;
  int t   = threadIdx.x;
  int i0 = tok[row], i1 = post[row], i2 = auth[row], i3 = act[row];
  int i4 = tg[row]; i4 = (i4 < 0) ? 0 : (i4 > 64 ? 64 : i4);
  int i5 = gidp[row];
  float v[6];
  v[0] = token_emb[(size_t)i0*Hh + t];
  v[1] = token_emb[(size_t)i1*Hh + t];
  v[2] = token_emb[(size_t)i2*Hh + t];
  v[3] = token_emb[(size_t)i3*Hh + t];
  v[4] = time_emb[i4*Hh + t];
  v[5] = group_emb[i5*Hh + t];
  float s=0.f, s2=0.f;
  #pragma unroll
  for (int i=0;i<6;i++){ s+=v[i]; s2+=v[i]*v[i]; }
  #pragma unroll
  for (int off=32; off; off>>=1){ s += __shfl_xor(s,off); s2 += __shfl_xor(s2,off); }
  __shared__ float rs[4], rs2[4];
  int w=t>>6;
  if ((t&63)==0){ rs[w]=s; rs2[w]=s2; }
  __syncthreads();
  s  = rs[0]+rs[1]+rs[2]+rs[3];
  s2 = rs2[0]+rs2[1]+rs2[2]+rs2[3];
  float mu   = s * (1.0f/1536.0f);
  float var  = s2 * (1.0f/1536.0f) - mu*mu;
  float rstd = rsqrtf(var + 1e-5f);
  unsigned short* xr = xn + (size_t)row*SIXH;
  #pragma unroll
  for (int i=0;i<6;i++){
    int j = i*Hh + t;
    float y = (v[i]-mu)*rstd*ln_g[j] + ln_b[j];
    xr[j] = f2bf(y);
  }
}

// ---------------------------------------------------------------------------
// GEMM1: 256x256 tile, 8 waves (4x2 grid, wave = 64 rows x 128 cols), BK=32,
// 4-slot LDS ring, ONE barrier per 2-K-tile WINDOW, and CROSS-WAVE STAGGER:
// waves 0-3 process the window's tiles as (t0,t1); waves 4-7 as (t1,t0).
// Waves w and w+4 share a SIMD, so each SIMD always hosts one reading wave
// and one MFMA-ing wave mid-window -> LDS-port drain overlaps the MFMA pipe
// via cross-wave concurrency (zero extra registers; per-wave read-ahead is
// register-impossible at acc=128). R1-R7 (identical per-wave program order)
// all pinned at 30-35% MfmaUtil = port+MFMA fully serialized.
// Ring safety: window w reads slots {2w&3,(2w+1)&3}, stages slots
// {(2w+2)&3,(2w+3)&3} — always disjoint pairs ({0,1} vs {2,3}); the
// end-of-window barrier (own lgkmcnt(0)+vmcnt(0) before it) publishes
// stages and retires reads before the pair roles swap.
// Swizzle (row stride 64B): granule g of row r stored at g ^ ((r>>1)&3)
// (R0-baseline-proven involution; 2-way bank aliasing = free).
// A [M][K] bf16, Bt [N][K] bf16, C = silu(A@Bt^T + bias) as bf16 [M][N].
__global__ __launch_bounds__(512, 2) void gemm1_sg_kernel(
  const unsigned short* __restrict__ A, const unsigned short* __restrict__ Bt,
  const float* __restrict__ bias, unsigned short* __restrict__ C,
  int M, int N, int K)
{
  __shared__ unsigned short lds[65536];   // A: 4 slots x 8192 elems; B at +32768

  int nbx = N >> 8;
  int bid = blockIdx.x;
  if ((gridDim.x & 7) == 0){                // XCD swizzle (bijective, nwg%8==0)
    int chunk = gridDim.x >> 3;
    bid = (bid & 7)*chunk + (bid >> 3);
  }
  int bx = bid % nbx, by = bid / nbx;
  int brow = by*256, bcol = bx*256;

  int tid = threadIdx.x, lane = tid & 63, wid = tid >> 6;
  int wr = wid >> 1, wc = wid & 1;          // 4 x 2 wave grid

  // ---- staging lane geometry: 128-row GL16 rounds (pre-swizzled global) ----
  int srow = tid >> 2;                      // 0..127
  int sg   = ((tid & 3) ^ ((tid >> 3) & 3)) << 3;  // swizzled granule (elems)
  const unsigned short* pAlo = A  + (size_t)(brow +       srow)*K + sg;
  const unsigned short* pAhi = A  + (size_t)(brow + 128 + srow)*K + sg;
  const unsigned short* pBlo = Bt + (size_t)(bcol +       srow)*K + sg;
  const unsigned short* pBhi = Bt + (size_t)(bcol + 128 + srow)*K + sg;

  // ---- per-lane fragment read bases (swizzled), in elements ----
  int fr = lane & 15, kb = lane >> 4;       // kb = 8-elem granule within K=32
  int gp = (kb ^ ((fr >> 1) & 3)) << 3;
  int aB = (wr*64  + fr)*32 + gp;
  int bB = (wc*128 + fr)*32 + gp;

  f32x4 acc[4][8];
  #pragma unroll
  for (int q=0;q<4;q++)
    #pragma unroll
    for (int n=0;n<8;n++) acc[q][n] = (f32x4){0.f,0.f,0.f,0.f};

  // Stage one K-tile (32KB = A 2 rounds + B 2 rounds) into slot S.
#define STAGE_TILE(S, OFF) do{ \
    int sa_ = (S)*8192, sb_ = 32768 + (S)*8192; \
    GL16(pAlo + (OFF), lds + sa_ + wid*512); \
    GL16(pAhi + (OFF), lds + sa_ + 4096 + wid*512); \
    GL16(pBlo + (OFF), lds + sb_ + wid*512); \
    GL16(pBhi + (OFF), lds + sb_ + 4096 + wid*512); }while(0)

  // One K-tile: 12 ds_read_b128 + 32 MFMA; compiler-scheduled interleave.
#define TILE(S) do{ \
    int sa_ = (S)*8192, sb_ = 32768 + (S)*8192; \
    bf16x8 a_[4], bP_[4], bQ_[4]; \
    _Pragma("unroll") for (int q=0;q<4;q++) \
      a_[q]  = *(const bf16x8*)(lds + sa_ + aB + q*512); \
    _Pragma("unroll") for (int n=0;n<4;n++) \
      bP_[n] = *(const bf16x8*)(lds + sb_ + bB + n*512); \
    _Pragma("unroll") for (int n=0;n<4;n++) \
      bQ_[n] = *(const bf16x8*)(lds + sb_ + 2048 + bB + n*512); \
    __builtin_amdgcn_s_setprio(1); \
    _Pragma("unroll") for (int q=0;q<4;q++) \
      _Pragma("unroll") for (int n=0;n<4;n++) \
        acc[q][n]   = __builtin_amdgcn_mfma_f32_16x16x32_bf16(a_[q], bP_[n], acc[q][n],   0,0,0); \
    _Pragma("unroll") for (int q=0;q<4;q++) \
      _Pragma("unroll") for (int n=0;n<4;n++) \
        acc[q][4+n] = __builtin_amdgcn_mfma_f32_16x16x32_bf16(a_[q], bQ_[n], acc[q][4+n], 0,0,0); \
    __builtin_amdgcn_s_setprio(0); \
  }while(0)

#define LGKM0 asm volatile("s_waitcnt lgkmcnt(0)" ::: "memory")
#define VM0   asm volatile("s_waitcnt vmcnt(0)" ::: "memory")
#define BAR   __builtin_amdgcn_s_barrier()
#define MFEN  asm volatile("" ::: "memory")

  // ---- prologue: stage window 0 (tiles 0,1 -> slots 0,1); publish ----
  STAGE_TILE(0, 0);
  STAGE_TILE(1, 32);
  VM0; BAR; MFEN;

  int nw = K >> 6;                          // 24 windows of 2 K-tiles
  for (int w = 0; w < nw; ++w){
    int s0 = (w & 1) << 1;                  // slot of tile 2w: 0 or 2
    int s1 = s0 + 1;
    if (w < nw-1){                          // stage next window into s^2 pair
      STAGE_TILE(s0 ^ 2, 64);
      STAGE_TILE(s1 ^ 2, 96);
    }
    if (wid < 4){ TILE(s0); TILE(s1); }     // group A: t0 then t1
    else        { TILE(s1); TILE(s0); }     // group B: t1 then t0 (stagger)
    LGKM0; VM0; BAR; MFEN;
    pAlo += 64; pAhi += 64; pBlo += 64; pBhi += 64;
  }

#undef TILE
#undef STAGE_TILE

  // ---- epilogue: C/D layout col=lane&15, row=(lane>>4)*4+j ----
  int colb = bcol + wc*128 + fr;
  float bv[8];
  #pragma unroll
  for (int n=0;n<8;n++) bv[n] = bias[colb + n*16];
  int r0 = brow + wr*64 + (lane>>4)*4;
  #pragma unroll
  for (int q=0;q<4;q++){
    #pragma unroll
    for (int j=0;j<4;j++){
      int r = r0 + q*16 + j;
      #pragma unroll
      for (int n=0;n<8;n++){
        float x = acc[q][n][j] + bv[n];
        x = x / (1.0f + expf(-x));
        C[(size_t)r*N + colb + n*16] = f2bf(x);
      }
    }
  }
}

// ---------------------------------------------------------------------------
// bf16 MFMA GEMM (m97 structure, 128x128): used for GEMM2.
template<bool SILU, bool OUT_BF16>
__global__ __launch_bounds__(256) void gemm_mfma_kernel(
  const unsigned short* __restrict__ A, const unsigned short* __restrict__ Bt,
  const float* __restrict__ bias, void* __restrict__ C,
  int M, int N, int K)
{
  __shared__ unsigned short As[128*32];
  __shared__ unsigned short Bs[128*32];
  int nbx = N >> 7;
  int bx = blockIdx.x % nbx;
  int by = blockIdx.x / nbx;
  int tid  = threadIdx.x;
  int lane = tid & 63;
  int wid  = tid >> 6;
  int wr = wid >> 1, wc = wid & 1;
  const int brow = by*128, bcol = bx*128;

  int g_r = lane >> 2;
  int g_k = (lane & 3) * 8;
  const unsigned short* Ag0 = A  + (size_t)(brow + wid*32 + g_r)*K + g_k;
  const unsigned short* Ag1 = Ag0 + (size_t)16*K;
  const unsigned short* Bg0 = Bt + (size_t)(bcol + wid*32 + g_r)*K + g_k;
  const unsigned short* Bg1 = Bg0 + (size_t)16*K;
  unsigned short* lA0 = &As[(wid*32 +  0)*32];
  unsigned short* lA1 = &As[(wid*32 + 16)*32];
  unsigned short* lB0 = &Bs[(wid*32 +  0)*32];
  unsigned short* lB1 = &Bs[(wid*32 + 16)*32];

  f32x4 acc[4][4];
  #pragma unroll
  for (int i=0;i<4;i++)
    #pragma unroll
    for (int j=0;j<4;j++) acc[i][j] = (f32x4){0.f,0.f,0.f,0.f};

  int fr = lane & 15;
  int fk = (lane >> 4) * 8;

  for (int kt = 0; kt < K; kt += 32){
    GL16(Ag0 + kt, lA0);
    GL16(Ag1 + kt, lA1);
    GL16(Bg0 + kt, lB0);
    GL16(Bg1 + kt, lB1);
    __syncthreads();
    bf16x8 af[4], bfr[4];
    #pragma unroll
    for (int i=0;i<4;i++){
      af[i]  = *(const bf16x8*)&As[(wr*64 + i*16 + fr)*32 + fk];
      bfr[i] = *(const bf16x8*)&Bs[(wc*64 + i*16 + fr)*32 + fk];
    }
    #pragma unroll
    for (int mi=0;mi<4;mi++)
      #pragma unroll
      for (int ni=0;ni<4;ni++)
        acc[mi][ni] = __builtin_amdgcn_mfma_f32_16x16x32_bf16(af[mi], bfr[ni], acc[mi][ni], 0, 0, 0);
    __syncthreads();
  }

  int col0 = bcol + wc*64 + (lane & 15);
  int row0 = brow + wr*64 + (lane >> 4)*4;
  #pragma unroll
  for (int mi=0;mi<4;mi++){
    #pragma unroll
    for (int j=0;j<4;j++){
      int r = row0 + mi*16 + j;
      #pragma unroll
      for (int ni=0;ni<4;ni++){
        int c = col0 + ni*16;
        float x = acc[mi][ni][j] + bias[c];
        if (SILU) x = x / (1.0f + expf(-x));
        if (OUT_BF16) ((unsigned short*)C)[(size_t)r*N + c] = f2bf(x);
        else          ((float*)C)[(size_t)r*N + c] = x;
      }
    }
  }
}

// ---------------------------------------------------------------------------
// Parallel merge metadata: one block of 512 threads per batch (thread = position).
__global__ __launch_bounds__(512) void merge_meta_kernel(
  const void* __restrict__ maskp, const int* __restrict__ gid,
  const int* __restrict__ flag,
  int* __restrict__ src, int* __restrict__ count)
{
  int b = blockIdx.x;
  int i = threadIdx.x;
  int lane = i & 63, w = i >> 6;
  __shared__ int sg[Ll_];
  __shared__ int fv[8];
  __shared__ int wt[8];
  int f = *flag;
  int mv;
  if (f==0)      mv = ((const int*)maskp)[b*Ll_+i];
  else if (f==1) mv = ((const unsigned char*)maskp)[b*Ll_+i];
  else           mv = (((const float*)maskp)[b*Ll_+i] != 0.0f);
  bool m = (mv != 0);
  int g = gid[b*Ll_+i];
  sg[i] = g;
  unsigned long long W = __ballot(m);
  if (lane==0) fv[w] = W ? (w*64 + __builtin_ctzll(W)) : -1;
  __syncthreads();
  unsigned long long rem = (lane==63) ? 0ull : (W >> (lane+1));
  int nxtpos = -1;
  if (rem) nxtpos = w*64 + lane + 1 + __builtin_ctzll(rem);
  else {
    #pragma unroll
    for (int k=0;k<8;k++)
      if (nxtpos < 0 && k > w && fv[k] >= 0) nxtpos = fv[k];
  }
  int nxt = (nxtpos >= 0) ? sg[nxtpos] : -1;
  bool sep = m && (nxt >= 0) && (nxt != g);
  int ci = (m?1:0) + (sep?1:0);
  int v = ci;
  #pragma unroll
  for (int off=1; off<64; off<<=1){
    int u = __shfl_up(v, off);
    if (lane >= off) v += u;
  }
  if (lane==63) wt[w] = v;
  __syncthreads();
  int woff = 0;
  #pragma unroll
  for (int k=0;k<8;k++) if (k < w) woff += wt[k];
  int e = woff + v - ci;
  int* sb = src + b*Mm_;
  if (m){
    sb[e] = 2*i;
    if (sep) sb[e+1] = 2*i+1;
  }
  if (i==0){
    int tot=0;
    #pragma unroll
    for (int k=0;k<8;k++) tot += wt[k];
    count[b] = tot;
  }
}

// ---------------------------------------------------------------------------
// Final output: right-aligned pieces + pos_emb, zeros elsewhere, plus mask plane.
__global__ __launch_bounds__(256) void output_kernel(
  const float* __restrict__ ev, const float* __restrict__ pos_emb,
  const float* __restrict__ sep_token,
  const int* __restrict__ src, const int* __restrict__ count,
  float* __restrict__ out)
{
  int tid  = threadIdx.x;
  int tpos = blockIdx.x*4 + (tid>>6);
  int lane = tid & 63;
  int b = tpos >> 10;
  int t = tpos & 1023;
  int cnt = count[b];
  int start = Mm_ - cnt;
  float4 val = make_float4(0.f,0.f,0.f,0.f);
  float maskv = 0.f;
  if (t >= start){
    maskv = 1.f;
    int slot = src[b*Mm_ + (t - start)];
    const float* sv = (slot & 1) ? sep_token
                                 : ev + (size_t)(b*Ll_ + (slot>>1))*Hh;
    float4 x = *(const float4*)(sv + lane*4);
    float4 p = *(const float4*)(pos_emb + (size_t)t*Hh + lane*4);
    val = make_float4(x.x+p.x, x.y+p.y, x.z+p.z, x.w+p.w);
  }
  *(float4*)(out + (size_t)tpos*Hh + lane*4) = val;
  if (lane==0) out[(size_t)Bb_*Mm_*Hh + tpos] = maskv;
}

// ---------------------------------------------------------------------------
extern "C" void kernel_launch(void* const* d_in, const int* in_sizes, int n_in,
                              void* d_out, int out_size, void* d_ws, size_t ws_size,
                              hipStream_t stream) {
  const int* tok    = (const int*)d_in[0];
  const int* post   = (const int*)d_in[1];
  const int* auth   = (const int*)d_in[2];
  const int* act    = (const int*)d_in[3];
  const int* tg     = (const int*)d_in[4];
  const int* gid    = (const int*)d_in[5];
  const void* maskp =             d_in[6];
  const float* token_emb = (const float*)d_in[7];
  const float* time_emb  = (const float*)d_in[8];
  const float* group_emb = (const float*)d_in[9];
  const float* pos_emb   = (const float*)d_in[10];
  const float* sep_token = (const float*)d_in[11];
  const float* ln_g = (const float*)d_in[12];
  const float* ln_b = (const float*)d_in[13];
  const float* W1   = (const float*)d_in[14];
  const float* b1   = (const float*)d_in[15];
  const float* W2   = (const float*)d_in[16];
  const float* b2   = (const float*)d_in[17];

  char* ws = (char*)d_ws;
  size_t off = 0;
  int* flag = (int*)ws;                                  off += 256;
  unsigned short* xn  = (unsigned short*)(ws + off);     off += (size_t)BL_*SIXH*2;
  unsigned short* h1  = (unsigned short*)(ws + off);     off += (size_t)BL_*N1_*2;
  float*          ev  = (float*)(ws + off);              off += (size_t)BL_*N2_*4;
  unsigned short* w1t = (unsigned short*)(ws + off);     off += (size_t)K1_*N1_*2;
  unsigned short* w2t = (unsigned short*)(ws + off);     off += (size_t)K2_*N2_*2;
  int*            src = (int*)(ws + off);                off += (size_t)Bb_*Mm_*4;
  int*            cnt = (int*)(ws + off);                off += 256;

  detect_mask_kernel<<<1,256,0,stream>>>((const unsigned int*)maskp, flag);
  transpose_conv_kernel<<<(K1_/32)*(N1_/32),256,0,stream>>>(W1, w1t, K1_, N1_);
  transpose_conv_kernel<<<(K2_/32)*(N2_/32),256,0,stream>>>(W2, w2t, K2_, N2_);
  gather_ln_kernel<<<BL_,256,0,stream>>>(tok,post,auth,act,tg,gid,
                                         token_emb,time_emb,group_emb,
                                         ln_g,ln_b,xn);
  gemm1_sg_kernel<<<(BL_/256)*(N1_/256),512,0,stream>>>(
      xn, w1t, b1, h1, BL_, N1_, K1_);
  gemm_mfma_kernel<false,false><<<(BL_/128)*(N2_/128),256,0,stream>>>(
      h1, w2t, b2, (void*)ev, BL_, N2_, K2_);
  merge_meta_kernel<<<Bb_,512,0,stream>>>(maskp, gid, flag, src, cnt);
  output_kernel<<<(Bb_*Mm_)/4,256,0,stream>>>(ev, pos_emb, sep_token, src, cnt, (float*)d_out);
}

// Round 9
// 114.419 us; speedup vs baseline: 1.2412x; 1.2412x over previous
//
#include <hip/hip_runtime.h>
#include <string.h>

// Problem constants (from reference setup_inputs)
#define Hh   256
#define SIXH 1536
#define Bb_  32
#define Ll_  512
#define BL_  16384   // B*L
#define Mm_  1024
#define N1_  1024    // 4H
#define K1_  1536    // 6H
#define K2_  1024
#define N2_  256

typedef __attribute__((ext_vector_type(8))) short bf16x8;
typedef __attribute__((ext_vector_type(4))) float f32x4;

__device__ inline float bf2f(unsigned short u){ unsigned x=(unsigned)u<<16; float f; memcpy(&f,&x,4); return f; }
__device__ inline unsigned short f2bf(float f){ unsigned x; memcpy(&x,&f,4); x = x + 0x7FFFu + ((x>>16)&1u); return (unsigned short)(x>>16); }

#define GL16(gp, lp) __builtin_amdgcn_global_load_lds( \
    (const __attribute__((address_space(1))) void*)(gp), \
    (__attribute__((address_space(3))) void*)(lp), 16, 0, 0)

// ---------------------------------------------------------------------------
// Fused prep kernel: block 0 = mask dtype detect (flag 0=int32,1=byte,2=f32);
// blocks 1..1536 = W1 transpose tiles; blocks 1537..1792 = W2 tiles.
// Transpose: W [K][N] f32 -> Wt [N][K] bf16, 32x32 tiles.
__global__ __launch_bounds__(256) void prep_kernel(
  const unsigned int* __restrict__ m, int* __restrict__ flag,
  const float* __restrict__ W1, unsigned short* __restrict__ W1t,
  const float* __restrict__ W2, unsigned short* __restrict__ W2t)
{
  int bidg = blockIdx.x;
  int t = threadIdx.x;
  if (bidg == 0){
    bool gt1=false, isf=false;
    for (int i=t;i<4096;i+=256){ unsigned v=m[i]; if(v>1u) gt1=true; if(v==0x3F800000u) isf=true; }
    unsigned long long bg = __ballot(gt1), bf = __ballot(isf);
    __shared__ unsigned long long s1[4], s2[4];
    int w = t>>6;
    if ((t&63)==0){ s1[w]=bg; s2[w]=bf; }
    __syncthreads();
    if (t==0){
      bool g = (s1[0]|s1[1]|s1[2]|s1[3])!=0ull;
      bool f = (s2[0]|s2[1]|s2[2]|s2[3])!=0ull;
      *flag = g ? (f?2:1) : 0;
    }
    return;
  }
  const float* W; unsigned short* Wt; int K, N, id;
  if (bidg <= (K1_/32)*(N1_/32)){ W = W1; Wt = W1t; K = K1_; N = N1_; id = bidg-1; }
  else { W = W2; Wt = W2t; K = K2_; N = N2_; id = bidg-1-(K1_/32)*(N1_/32); }
  __shared__ float tl[32][33];
  int ntx = N >> 5;
  int bx = id % ntx;
  int by = id / ntx;
  int tx = t & 31, ty = t >> 5;
  #pragma unroll
  for (int i=0;i<32;i+=8)
    tl[ty+i][tx] = W[(size_t)(by*32+ty+i)*N + bx*32+tx];
  __syncthreads();
  #pragma unroll
  for (int i=0;i<32;i+=8)
    Wt[(size_t)(bx*32+ty+i)*K + by*32+tx] = f2bf(tl[tx][ty+i]);
}

// ---------------------------------------------------------------------------
// Vectorized gather + LayerNorm(1536) -> xn bf16 [16384][1536].
// 2 rows per block; per row 2 waves; each lane loads float4 (16B) from 3
// segments and writes ushort4 (8B) packed bf16.  (G13: vectorize always.)
__global__ __launch_bounds__(256) void gather_ln2_kernel(
  const int* __restrict__ tok, const int* __restrict__ post,
  const int* __restrict__ auth, const int* __restrict__ act,
  const int* __restrict__ tg,  const int* __restrict__ gidp,
  const float* __restrict__ token_emb, const float* __restrict__ time_emb,
  const float* __restrict__ group_emb,
  const float* __restrict__ ln_g, const float* __restrict__ ln_b,
  unsigned short* __restrict__ xn)
{
  int t = threadIdx.x;
  int rib = t >> 7;                       // row in block (0/1)
  int row = blockIdx.x*2 + rib;
  int wai = (t >> 6) & 1;                 // wave within row
  int l   = t & 63;

  // Segments handled by this half: wai + {0,2,4}
  int e0 = wai ? post[row] : tok[row];
  int e1 = wai ? act[row]  : auth[row];
  const float* b2p;
  if (wai == 0){
    int i4 = tg[row]; i4 = (i4 < 0) ? 0 : (i4 > 64 ? 64 : i4);
    b2p = time_emb + (size_t)i4*Hh;
  } else {
    b2p = group_emb + (size_t)gidp[row]*Hh;
  }
  const float* b0p = token_emb + (size_t)e0*Hh;
  const float* b1p = token_emb + (size_t)e1*Hh;

  float4 v0 = *(const float4*)(b0p + l*4);
  float4 v1 = *(const float4*)(b1p + l*4);
  float4 v2 = *(const float4*)(b2p + l*4);

  float s  = v0.x+v0.y+v0.z+v0.w + v1.x+v1.y+v1.z+v1.w + v2.x+v2.y+v2.z+v2.w;
  float s2 = v0.x*v0.x+v0.y*v0.y+v0.z*v0.z+v0.w*v0.w
           + v1.x*v1.x+v1.y*v1.y+v1.z*v1.z+v1.w*v1.w
           + v2.x*v2.x+v2.y*v2.y+v2.z*v2.z+v2.w*v2.w;
  #pragma unroll
  for (int off=32; off; off>>=1){ s += __shfl_xor(s,off); s2 += __shfl_xor(s2,off); }

  __shared__ float rs[2][2], rq[2][2];
  if (l==0){ rs[rib][wai] = s; rq[rib][wai] = s2; }
  __syncthreads();
  s  = rs[rib][0] + rs[rib][1];
  s2 = rq[rib][0] + rq[rib][1];
  float mu   = s * (1.0f/1536.0f);
  float var  = s2 * (1.0f/1536.0f) - mu*mu;
  float rstd = rsqrtf(var + 1e-5f);

  unsigned short* xr = xn + (size_t)row*SIXH;
  #pragma unroll
  for (int p=0;p<3;p++){
    int seg = p*2 + wai;
    int j = seg*Hh + l*4;
    float4 g4 = *(const float4*)(ln_g + j);
    float4 bb = *(const float4*)(ln_b + j);
    float4 v = (p==0) ? v0 : (p==1) ? v1 : v2;
    ushort4 o;
    o.x = f2bf((v.x-mu)*rstd*g4.x + bb.x);
    o.y = f2bf((v.y-mu)*rstd*g4.y + bb.y);
    o.z = f2bf((v.z-mu)*rstd*g4.z + bb.z);
    o.w = f2bf((v.w-mu)*rstd*g4.w + bb.w);
    *(ushort4*)(xr + j) = o;
  }
}

// ---------------------------------------------------------------------------
// GEMM1 (R7, best measured): 256x256 tile, 8 waves (4x2), BK=64,
// compiler-scheduled tile body, one lgkmcnt(0)+vmcnt(0)+barrier per K-tile.
// Swizzle: 16B granule g of row r stored at g ^ (r&7) (involution both sides).
// A [M][K] bf16, Bt [N][K] bf16, C = silu(A@Bt^T + bias) as bf16 [M][N].
__global__ __launch_bounds__(512, 2) void gemm1_cs_kernel(
  const unsigned short* __restrict__ A, const unsigned short* __restrict__ Bt,
  const float* __restrict__ bias, unsigned short* __restrict__ C,
  int M, int N, int K)
{
  __shared__ unsigned short lds[65536];

  int nbx = N >> 8;
  int bid = blockIdx.x;
  if ((gridDim.x & 7) == 0){                // XCD swizzle (bijective, nwg%8==0)
    int chunk = gridDim.x >> 3;
    bid = (bid & 7)*chunk + (bid >> 3);
  }
  int bx = bid % nbx, by = bid / nbx;
  int brow = by*256, bcol = bx*256;

  int tid = threadIdx.x, lane = tid & 63, wid = tid >> 6;
  int wr = wid >> 1, wc = wid & 1;          // 4 x 2 wave grid

  int sRow = tid >> 3;                      // 0..63
  int sSw  = ((tid & 7) ^ (sRow & 7)) << 3; // swizzled granule (elements)
  const unsigned short* pA0 = A  + (size_t)(brow +   0 + sRow)*K + sSw;
  const unsigned short* pA1 = A  + (size_t)(brow +  64 + sRow)*K + sSw;
  const unsigned short* pA2 = A  + (size_t)(brow + 128 + sRow)*K + sSw;
  const unsigned short* pA3 = A  + (size_t)(brow + 192 + sRow)*K + sSw;
  const unsigned short* pB0 = Bt + (size_t)(bcol +   0 + sRow)*K + sSw;
  const unsigned short* pB1 = Bt + (size_t)(bcol +  64 + sRow)*K + sSw;
  const unsigned short* pB2 = Bt + (size_t)(bcol + 128 + sRow)*K + sSw;
  const unsigned short* pB3 = Bt + (size_t)(bcol + 192 + sRow)*K + sSw;

  int fr = lane & 15, kb = lane >> 4;
  int g0 = (kb ^ (fr & 3)) | (fr & 4);      // = kb ^ (fr&7); kc=1 -> addr ^32
  int aB = (wr*64  + fr)*64 + g0*8;
  int bB = (wc*128 + fr)*64 + g0*8;

  f32x4 acc[4][8];
  #pragma unroll
  for (int q=0;q<4;q++)
    #pragma unroll
    for (int n=0;n<8;n++) acc[q][n] = (f32x4){0.f,0.f,0.f,0.f};

  bf16x8 a0[4], a1[4], bP[4], bQ[4];

#define ABASE(S) ((S)*16384)
#define BBASE(S) (32768 + (S)*16384)

#define RD_A(buf, S, kc) do{ \
    const unsigned short* L_ = lds + ABASE(S) + (aB ^ ((kc)?32:0)); \
    buf[0] = *(const bf16x8*)(L_); \
    buf[1] = *(const bf16x8*)(L_ + 1024); \
    buf[2] = *(const bf16x8*)(L_ + 2048); \
    buf[3] = *(const bf16x8*)(L_ + 3072); }while(0)

#define RD_B(buf, S, h, kc) do{ \
    const unsigned short* L_ = lds + BBASE(S) + (h)*4096 + (bB ^ ((kc)?32:0)); \
    buf[0] = *(const bf16x8*)(L_); \
    buf[1] = *(const bf16x8*)(L_ + 1024); \
    buf[2] = *(const bf16x8*)(L_ + 2048); \
    buf[3] = *(const bf16x8*)(L_ + 3072); }while(0)

#define STG(p, DB, OFF) GL16((p) + (OFF), lds + (DB) + wid*512)

#define MMX(AF, BF, NB) do{ \
    _Pragma("unroll") for (int q=0;q<4;q++) \
      _Pragma("unroll") for (int nn=0;nn<4;nn++) \
        acc[q][(NB)+nn] = __builtin_amdgcn_mfma_f32_16x16x32_bf16( \
            AF[q], BF[nn], acc[q][(NB)+nn], 0, 0, 0); }while(0)

#define LGKM0 asm volatile("s_waitcnt lgkmcnt(0)" ::: "memory")
#define BAR  __builtin_amdgcn_s_barrier()
#define VM0  asm volatile("s_waitcnt vmcnt(0)" ::: "memory")
#define VNOP do{}while(0)

#define TILE(S, OB1, SP, V4) do{ \
    if (SP){ \
      STG(pA0, ABASE((S)^1) + 0,     OB1); \
      STG(pA1, ABASE((S)^1) + 4096,  OB1); \
      STG(pA2, ABASE((S)^1) + 8192,  OB1); \
      STG(pA3, ABASE((S)^1) + 12288, OB1); \
      STG(pB0, BBASE((S)^1) + 0,     OB1); \
      STG(pB1, BBASE((S)^1) + 4096,  OB1); \
      STG(pB2, BBASE((S)^1) + 8192,  OB1); \
      STG(pB3, BBASE((S)^1) + 12288, OB1); } \
    RD_A(a0, S, 0); RD_B(bP, S, 0, 0); RD_B(bQ, S, 1, 0); \
    MMX(a0, bP, 0); \
    RD_A(a1, S, 1); RD_B(bP, S, 1, 1); \
    MMX(a0, bQ, 4); \
    RD_B(bQ, S, 0, 1); \
    MMX(a1, bP, 4); \
    MMX(a1, bQ, 0); \
    LGKM0; V4; BAR; \
    asm volatile("" ::: "memory"); \
  }while(0)

  int nk = K >> 6;                          // 24 K-tiles
  STG(pA0, ABASE(0)+0, 0);     STG(pA1, ABASE(0)+4096, 0);
  STG(pA2, ABASE(0)+8192, 0);  STG(pA3, ABASE(0)+12288, 0);
  STG(pB0, BBASE(0)+0, 0);     STG(pB1, BBASE(0)+4096, 0);
  STG(pB2, BBASE(0)+8192, 0);  STG(pB3, BBASE(0)+12288, 0);
  VM0; BAR;
  asm volatile("" ::: "memory");

  for (int tt = 0; tt < (nk-2)/2; ++tt){
    TILE(0,  64, 1, VM0);
    TILE(1, 128, 1, VM0);
    pA0 += 128; pA1 += 128; pA2 += 128; pA3 += 128;
    pB0 += 128; pB1 += 128; pB2 += 128; pB3 += 128;
  }
  TILE(0, 64, 1, VM0);
  TILE(1, 0, 0, VNOP);

#undef TILE
#undef RD_A
#undef RD_B
#undef STG
#undef MMX

  int colb = bcol + wc*128 + fr;
  float bv[8];
  #pragma unroll
  for (int n=0;n<8;n++) bv[n] = bias[colb + n*16];
  int r0 = brow + wr*64 + (lane>>4)*4;
  #pragma unroll
  for (int q=0;q<4;q++){
    #pragma unroll
    for (int j=0;j<4;j++){
      int r = r0 + q*16 + j;
      #pragma unroll
      for (int n=0;n<8;n++){
        float x = acc[q][n][j] + bv[n];
        x = x / (1.0f + expf(-x));
        C[(size_t)r*N + colb + n*16] = f2bf(x);
      }
    }
  }
}

// ---------------------------------------------------------------------------
// GEMM2: 64x64 tile, 256 threads (4 waves 2x2, wave-tile 32x32), BK=64,
// m97-style single-buffered global_load_lds staging.  Grid = 1024 blocks =
// 4 blocks/CU (old 128x128 grid was 256 = 1/CU = 12.5% occupancy, grid-
// starved); cross-block wave overlap hides the barrier drains.
// Swizzle: granule g of row r stored at g ^ (r&7) (same as gemm1).
// A [M][K] bf16, Bt [N][K] bf16, C = A@Bt^T + bias as f32 [M][N].
__global__ __launch_bounds__(256) void gemm2_64_kernel(
  const unsigned short* __restrict__ A, const unsigned short* __restrict__ Bt,
  const float* __restrict__ bias, float* __restrict__ C,
  int M, int N, int K)
{
  __shared__ unsigned short As[4096];
  __shared__ unsigned short Bs[4096];
  int nbx = N >> 6;
  int bid = blockIdx.x;
  if ((gridDim.x & 7) == 0){
    int chunk = gridDim.x >> 3;
    bid = (bid & 7)*chunk + (bid >> 3);
  }
  int bx = bid % nbx, by = bid / nbx;
  int brow = by*64, bcol = bx*64;
  int tid = threadIdx.x, lane = tid & 63, wid = tid >> 6;
  int wr = wid >> 1, wc = wid & 1;

  int srow = tid >> 3;                      // 0..31
  int sg   = ((tid & 7) ^ (srow & 7)) << 3;
  const unsigned short* pA0 = A  + (size_t)(brow + srow)*K + sg;
  const unsigned short* pA1 = pA0 + (size_t)32*K;
  const unsigned short* pB0 = Bt + (size_t)(bcol + srow)*K + sg;
  const unsigned short* pB1 = pB0 + (size_t)32*K;

  int fr = lane & 15, kb = lane >> 4;
  int g0 = (kb ^ (fr & 7)) << 3;
  int aB = (wr*32 + fr)*64 + g0;
  int bB = (wc*32 + fr)*64 + g0;

  f32x4 acc[2][2];
  #pragma unroll
  for (int i=0;i<2;i++)
    #pragma unroll
    for (int j=0;j<2;j++) acc[i][j] = (f32x4){0.f,0.f,0.f,0.f};

  for (int kt = 0; kt < K; kt += 64){
    GL16(pA0 + kt, As + wid*512);
    GL16(pA1 + kt, As + 2048 + wid*512);
    GL16(pB0 + kt, Bs + wid*512);
    GL16(pB1 + kt, Bs + 2048 + wid*512);
    __syncthreads();
    bf16x8 a[2][2], b[2][2];
    #pragma unroll
    for (int m=0;m<2;m++)
      #pragma unroll
      for (int kc=0;kc<2;kc++){
        a[m][kc] = *(const bf16x8*)(As + ((aB + m*1024) ^ (kc<<5)));
        b[m][kc] = *(const bf16x8*)(Bs + ((bB + m*1024) ^ (kc<<5)));
      }
    #pragma unroll
    for (int kc=0;kc<2;kc++)
      #pragma unroll
      for (int m=0;m<2;m++)
        #pragma unroll
        for (int n=0;n<2;n++)
          acc[m][n] = __builtin_amdgcn_mfma_f32_16x16x32_bf16(a[m][kc], b[n][kc], acc[m][n], 0, 0, 0);
    __syncthreads();
  }

  int col0 = bcol + wc*32 + fr;
  int row0 = brow + wr*32 + (lane >> 4)*4;
  #pragma unroll
  for (int m=0;m<2;m++){
    #pragma unroll
    for (int j=0;j<4;j++){
      int r = row0 + m*16 + j;
      #pragma unroll
      for (int n=0;n<2;n++){
        int c = col0 + n*16;
        C[(size_t)r*N + c] = acc[m][n][j] + bias[c];
      }
    }
  }
}

// ---------------------------------------------------------------------------
// Parallel merge metadata: one block of 512 threads per batch (thread = position).
__global__ __launch_bounds__(512) void merge_meta_kernel(
  const void* __restrict__ maskp, const int* __restrict__ gid,
  const int* __restrict__ flag,
  int* __restrict__ src, int* __restrict__ count)
{
  int b = blockIdx.x;
  int i = threadIdx.x;
  int lane = i & 63, w = i >> 6;
  __shared__ int sg[Ll_];
  __shared__ int fv[8];
  __shared__ int wt[8];
  int f = *flag;
  int mv;
  if (f==0)      mv = ((const int*)maskp)[b*Ll_+i];
  else if (f==1) mv = ((const unsigned char*)maskp)[b*Ll_+i];
  else           mv = (((const float*)maskp)[b*Ll_+i] != 0.0f);
  bool m = (mv != 0);
  int g = gid[b*Ll_+i];
  sg[i] = g;
  unsigned long long W = __ballot(m);
  if (lane==0) fv[w] = W ? (w*64 + __builtin_ctzll(W)) : -1;
  __syncthreads();
  unsigned long long rem = (lane==63) ? 0ull : (W >> (lane+1));
  int nxtpos = -1;
  if (rem) nxtpos = w*64 + lane + 1 + __builtin_ctzll(rem);
  else {
    #pragma unroll
    for (int k=0;k<8;k++)
      if (nxtpos < 0 && k > w && fv[k] >= 0) nxtpos = fv[k];
  }
  int nxt = (nxtpos >= 0) ? sg[nxtpos] : -1;
  bool sep = m && (nxt >= 0) && (nxt != g);
  int ci = (m?1:0) + (sep?1:0);
  int v = ci;
  #pragma unroll
  for (int off=1; off<64; off<<=1){
    int u = __shfl_up(v, off);
    if (lane >= off) v += u;
  }
  if (lane==63) wt[w] = v;
  __syncthreads();
  int woff = 0;
  #pragma unroll
  for (int k=0;k<8;k++) if (k < w) woff += wt[k];
  int e = woff + v - ci;
  int* sb = src + b*Mm_;
  if (m){
    sb[e] = 2*i;
    if (sep) sb[e+1] = 2*i+1;
  }
  if (i==0){
    int tot=0;
    #pragma unroll
    for (int k=0;k<8;k++) tot += wt[k];
    count[b] = tot;
  }
}

// ---------------------------------------------------------------------------
// Final output: right-aligned pieces + pos_emb, zeros elsewhere, plus mask plane.
__global__ __launch_bounds__(256) void output_kernel(
  const float* __restrict__ ev, const float* __restrict__ pos_emb,
  const float* __restrict__ sep_token,
  const int* __restrict__ src, const int* __restrict__ count,
  float* __restrict__ out)
{
  int tid  = threadIdx.x;
  int tpos = blockIdx.x*4 + (tid>>6);
  int lane = tid & 63;
  int b = tpos >> 10;
  int t = tpos & 1023;
  int cnt = count[b];
  int start = Mm_ - cnt;
  float4 val = make_float4(0.f,0.f,0.f,0.f);
  float maskv = 0.f;
  if (t >= start){
    maskv = 1.f;
    int slot = src[b*Mm_ + (t - start)];
    const float* sv = (slot & 1) ? sep_token
                                 : ev + (size_t)(b*Ll_ + (slot>>1))*Hh;
    float4 x = *(const float4*)(sv + lane*4);
    float4 p = *(const float4*)(pos_emb + (size_t)t*Hh + lane*4);
    val = make_float4(x.x+p.x, x.y+p.y, x.z+p.z, x.w+p.w);
  }
  *(float4*)(out + (size_t)tpos*Hh + lane*4) = val;
  if (lane==0) out[(size_t)Bb_*Mm_*Hh + tpos] = maskv;
}

// ---------------------------------------------------------------------------
extern "C" void kernel_launch(void* const* d_in, const int* in_sizes, int n_in,
                              void* d_out, int out_size, void* d_ws, size_t ws_size,
                              hipStream_t stream) {
  const int* tok    = (const int*)d_in[0];
  const int* post   = (const int*)d_in[1];
  const int* auth   = (const int*)d_in[2];
  const int* act    = (const int*)d_in[3];
  const int* tg     = (const int*)d_in[4];
  const int* gid    = (const int*)d_in[5];
  const void* maskp =             d_in[6];
  const float* token_emb = (const float*)d_in[7];
  const float* time_emb  = (const float*)d_in[8];
  const float* group_emb = (const float*)d_in[9];
  const float* pos_emb   = (const float*)d_in[10];
  const float* sep_token = (const float*)d_in[11];
  const float* ln_g = (const float*)d_in[12];
  const float* ln_b = (const float*)d_in[13];
  const float* W1   = (const float*)d_in[14];
  const float* b1   = (const float*)d_in[15];
  const float* W2   = (const float*)d_in[16];
  const float* b2   = (const float*)d_in[17];

  char* ws = (char*)d_ws;
  size_t off = 0;
  int* flag = (int*)ws;                                  off += 256;
  unsigned short* xn  = (unsigned short*)(ws + off);     off += (size_t)BL_*SIXH*2;
  unsigned short* h1  = (unsigned short*)(ws + off);     off += (size_t)BL_*N1_*2;
  float*          ev  = (float*)(ws + off);              off += (size_t)BL_*N2_*4;
  unsigned short* w1t = (unsigned short*)(ws + off);     off += (size_t)K1_*N1_*2;
  unsigned short* w2t = (unsigned short*)(ws + off);     off += (size_t)K2_*N2_*2;
  int*            src = (int*)(ws + off);                off += (size_t)Bb_*Mm_*4;
  int*            cnt = (int*)(ws + off);                off += 256;

  const int PREP_BLOCKS = 1 + (K1_/32)*(N1_/32) + (K2_/32)*(N2_/32);  // 1793
  prep_kernel<<<PREP_BLOCKS,256,0,stream>>>((const unsigned int*)maskp, flag,
                                            W1, w1t, W2, w2t);
  gather_ln2_kernel<<<BL_/2,256,0,stream>>>(tok,post,auth,act,tg,gid,
                                            token_emb,time_emb,group_emb,
                                            ln_g,ln_b,xn);
  gemm1_cs_kernel<<<(BL_/256)*(N1_/256),512,0,stream>>>(
      xn, w1t, b1, h1, BL_, N1_, K1_);
  gemm2_64_kernel<<<(BL_/64)*(N2_/64),256,0,stream>>>(
      h1, w2t, b2, ev, BL_, N2_, K2_);
  merge_meta_kernel<<<Bb_,512,0,stream>>>(maskp, gid, flag, src, cnt);
  output_kernel<<<(Bb_*Mm_)/4,256,0,stream>>>(ev, pos_emb, sep_token, src, cnt, (float*)d_out);
}

// Round 10
// 105.769 us; speedup vs baseline: 1.3427x; 1.0818x over previous
//
#include <hip/hip_runtime.h>
#include <string.h>

// Problem constants (from reference setup_inputs)
#define Hh   256
#define SIXH 1536
#define Bb_  32
#define Ll_  512
#define BL_  16384   // B*L
#define Mm_  1024
#define N1_  1024    // 4H
#define K1_  1536    // 6H
#define K2_  1024
#define N2_  256

typedef __attribute__((ext_vector_type(8))) short bf16x8;
typedef __attribute__((ext_vector_type(4))) float f32x4;

__device__ inline float bf2f(unsigned short u){ unsigned x=(unsigned)u<<16; float f; memcpy(&f,&x,4); return f; }
__device__ inline unsigned short f2bf(float f){ unsigned x; memcpy(&x,&f,4); x = x + 0x7FFFu + ((x>>16)&1u); return (unsigned short)(x>>16); }

#define GL16(gp, lp) __builtin_amdgcn_global_load_lds( \
    (const __attribute__((address_space(1))) void*)(gp), \
    (__attribute__((address_space(3))) void*)(lp), 16, 0, 0)

// ---------------------------------------------------------------------------
// Fused pre-GEMM mega-kernel (512 threads):
//   blocks 0..31     : merge metadata per batch (with INLINE mask-dtype detect
//                      — no cross-block flag dependency)
//   blocks 32..927   : W1/W2 transpose+bf16 tiles, 2 tiles per block
//   blocks 928..5023 : gather+LayerNorm, 4 rows per block (vectorized 16B/lane)
// All three phases are independent; fusing hides merge's 32-block latency
// under gather's bulk and removes 2 kernel launches.
__global__ __launch_bounds__(512) void fused_pre_kernel(
  const int* __restrict__ tok, const int* __restrict__ post,
  const int* __restrict__ auth, const int* __restrict__ act,
  const int* __restrict__ tg,  const int* __restrict__ gidp,
  const void* __restrict__ maskp,
  const float* __restrict__ token_emb, const float* __restrict__ time_emb,
  const float* __restrict__ group_emb,
  const float* __restrict__ ln_g, const float* __restrict__ ln_b,
  const float* __restrict__ W1, unsigned short* __restrict__ W1t,
  const float* __restrict__ W2, unsigned short* __restrict__ W2t,
  unsigned short* __restrict__ xn,
  int* __restrict__ src, int* __restrict__ count)
{
  int bid = blockIdx.x;
  int t   = threadIdx.x;

  if (bid < 32){
    // ---------------- merge metadata (one batch per block) ----------------
    int b = bid;
    int i = t;
    int lane = i & 63, w = i >> 6;
    // inline dtype detect: scan first 4096 uints of mask (covers byte-mask
    // fully; int32/f32 ambiguity resolved by value patterns, as before)
    bool gt1=false, isf=false;
    for (int k=t;k<4096;k+=512){
      unsigned v=((const unsigned int*)maskp)[k];
      if(v>1u) gt1=true; if(v==0x3F800000u) isf=true;
    }
    __shared__ unsigned long long d1[8], d2[8];
    unsigned long long bg=__ballot(gt1), bff=__ballot(isf);
    if (lane==0){ d1[w]=bg; d2[w]=bff; }
    __syncthreads();
    unsigned long long og=0, of=0;
    #pragma unroll
    for (int k=0;k<8;k++){ og|=d1[k]; of|=d2[k]; }
    int f = og ? (of?2:1) : 0;

    __shared__ int sg[Ll_];
    __shared__ int fv[8];
    __shared__ int wt[8];
    int mv;
    if (f==0)      mv = ((const int*)maskp)[b*Ll_+i];
    else if (f==1) mv = ((const unsigned char*)maskp)[b*Ll_+i];
    else           mv = (((const float*)maskp)[b*Ll_+i] != 0.0f);
    bool m = (mv != 0);
    int g = gidp[b*Ll_+i];
    sg[i] = g;
    unsigned long long W = __ballot(m);
    if (lane==0) fv[w] = W ? (w*64 + __builtin_ctzll(W)) : -1;
    __syncthreads();
    unsigned long long rem = (lane==63) ? 0ull : (W >> (lane+1));
    int nxtpos = -1;
    if (rem) nxtpos = w*64 + lane + 1 + __builtin_ctzll(rem);
    else {
      #pragma unroll
      for (int k=0;k<8;k++)
        if (nxtpos < 0 && k > w && fv[k] >= 0) nxtpos = fv[k];
    }
    int nxt = (nxtpos >= 0) ? sg[nxtpos] : -1;
    bool sep = m && (nxt >= 0) && (nxt != g);
    int ci = (m?1:0) + (sep?1:0);
    int v = ci;
    #pragma unroll
    for (int off=1; off<64; off<<=1){
      int u = __shfl_up(v, off);
      if (lane >= off) v += u;
    }
    if (lane==63) wt[w] = v;
    __syncthreads();
    int woff = 0;
    #pragma unroll
    for (int k=0;k<8;k++) if (k < w) woff += wt[k];
    int e = woff + v - ci;
    int* sb = src + b*Mm_;
    if (m){
      sb[e] = 2*i;
      if (sep) sb[e+1] = 2*i+1;
    }
    if (i==0){
      int tot=0;
      #pragma unroll
      for (int k=0;k<8;k++) tot += wt[k];
      count[b] = tot;
    }
    return;
  }

  if (bid < 928){
    // ---------------- W transpose (2 tiles per block) ----------------
    int half = t >> 8;              // 0/1
    int tt = t & 255;
    int id = (bid-32)*2 + half;     // 0..1791
    const float* W; unsigned short* Wt; int K, N, tid2;
    if (id < (K1_/32)*(N1_/32)){ W = W1; Wt = W1t; K = K1_; N = N1_; tid2 = id; }
    else { W = W2; Wt = W2t; K = K2_; N = N2_; tid2 = id - (K1_/32)*(N1_/32); }
    __shared__ float tl[2][32][33];
    int ntx = N >> 5;
    int bx = tid2 % ntx;
    int by = tid2 / ntx;
    int tx = tt & 31, ty = tt >> 5;
    #pragma unroll
    for (int i2=0;i2<32;i2+=8)
      tl[half][ty+i2][tx] = W[(size_t)(by*32+ty+i2)*N + bx*32+tx];
    __syncthreads();
    #pragma unroll
    for (int i2=0;i2<32;i2+=8)
      Wt[(size_t)(bx*32+ty+i2)*K + by*32+tx] = f2bf(tl[half][tx][ty+i2]);
    return;
  }

  // ---------------- gather + LayerNorm (4 rows per block) ----------------
  int rb  = bid - 928;              // 0..4095
  int rib = t >> 7;                 // row in block 0..3
  int row = rb*4 + rib;
  int wai = (t >> 6) & 1;           // wave within row
  int l   = t & 63;

  int e0 = wai ? post[row] : tok[row];
  int e1 = wai ? act[row]  : auth[row];
  const float* b2p;
  if (wai == 0){
    int i4 = tg[row]; i4 = (i4 < 0) ? 0 : (i4 > 64 ? 64 : i4);
    b2p = time_emb + (size_t)i4*Hh;
  } else {
    b2p = group_emb + (size_t)gidp[row]*Hh;
  }
  const float* b0p = token_emb + (size_t)e0*Hh;
  const float* b1p = token_emb + (size_t)e1*Hh;

  float4 v0 = *(const float4*)(b0p + l*4);
  float4 v1 = *(const float4*)(b1p + l*4);
  float4 v2 = *(const float4*)(b2p + l*4);

  float s  = v0.x+v0.y+v0.z+v0.w + v1.x+v1.y+v1.z+v1.w + v2.x+v2.y+v2.z+v2.w;
  float s2 = v0.x*v0.x+v0.y*v0.y+v0.z*v0.z+v0.w*v0.w
           + v1.x*v1.x+v1.y*v1.y+v1.z*v1.z+v1.w*v1.w
           + v2.x*v2.x+v2.y*v2.y+v2.z*v2.z+v2.w*v2.w;
  #pragma unroll
  for (int off=32; off; off>>=1){ s += __shfl_xor(s,off); s2 += __shfl_xor(s2,off); }

  __shared__ float rs[4][2], rq[4][2];
  if (l==0){ rs[rib][wai] = s; rq[rib][wai] = s2; }
  __syncthreads();
  s  = rs[rib][0] + rs[rib][1];
  s2 = rq[rib][0] + rq[rib][1];
  float mu   = s * (1.0f/1536.0f);
  float var  = s2 * (1.0f/1536.0f) - mu*mu;
  float rstd = rsqrtf(var + 1e-5f);

  unsigned short* xr = xn + (size_t)row*SIXH;
  #pragma unroll
  for (int p=0;p<3;p++){
    int seg = p*2 + wai;
    int j = seg*Hh + l*4;
    float4 g4 = *(const float4*)(ln_g + j);
    float4 bb = *(const float4*)(ln_b + j);
    float4 v = (p==0) ? v0 : (p==1) ? v1 : v2;
    ushort4 o;
    o.x = f2bf((v.x-mu)*rstd*g4.x + bb.x);
    o.y = f2bf((v.y-mu)*rstd*g4.y + bb.y);
    o.z = f2bf((v.z-mu)*rstd*g4.z + bb.z);
    o.w = f2bf((v.w-mu)*rstd*g4.w + bb.w);
    *(ushort4*)(xr + j) = o;
  }
}

// ---------------------------------------------------------------------------
// GEMM1 (R7, best measured): 256x256 tile, 8 waves (4x2), BK=64,
// compiler-scheduled tile body, one lgkmcnt(0)+vmcnt(0)+barrier per K-tile.
// Swizzle: 16B granule g of row r stored at g ^ (r&7) (involution both sides).
// A [M][K] bf16, Bt [N][K] bf16, C = silu(A@Bt^T + bias) as bf16 [M][N].
__global__ __launch_bounds__(512, 2) void gemm1_cs_kernel(
  const unsigned short* __restrict__ A, const unsigned short* __restrict__ Bt,
  const float* __restrict__ bias, unsigned short* __restrict__ C,
  int M, int N, int K)
{
  __shared__ unsigned short lds[65536];

  int nbx = N >> 8;
  int bid = blockIdx.x;
  if ((gridDim.x & 7) == 0){                // XCD swizzle (bijective, nwg%8==0)
    int chunk = gridDim.x >> 3;
    bid = (bid & 7)*chunk + (bid >> 3);
  }
  int bx = bid % nbx, by = bid / nbx;
  int brow = by*256, bcol = bx*256;

  int tid = threadIdx.x, lane = tid & 63, wid = tid >> 6;
  int wr = wid >> 1, wc = wid & 1;          // 4 x 2 wave grid

  int sRow = tid >> 3;                      // 0..63
  int sSw  = ((tid & 7) ^ (sRow & 7)) << 3; // swizzled granule (elements)
  const unsigned short* pA0 = A  + (size_t)(brow +   0 + sRow)*K + sSw;
  const unsigned short* pA1 = A  + (size_t)(brow +  64 + sRow)*K + sSw;
  const unsigned short* pA2 = A  + (size_t)(brow + 128 + sRow)*K + sSw;
  const unsigned short* pA3 = A  + (size_t)(brow + 192 + sRow)*K + sSw;
  const unsigned short* pB0 = Bt + (size_t)(bcol +   0 + sRow)*K + sSw;
  const unsigned short* pB1 = Bt + (size_t)(bcol +  64 + sRow)*K + sSw;
  const unsigned short* pB2 = Bt + (size_t)(bcol + 128 + sRow)*K + sSw;
  const unsigned short* pB3 = Bt + (size_t)(bcol + 192 + sRow)*K + sSw;

  int fr = lane & 15, kb = lane >> 4;
  int g0 = (kb ^ (fr & 3)) | (fr & 4);      // = kb ^ (fr&7); kc=1 -> addr ^32
  int aB = (wr*64  + fr)*64 + g0*8;
  int bB = (wc*128 + fr)*64 + g0*8;

  f32x4 acc[4][8];
  #pragma unroll
  for (int q=0;q<4;q++)
    #pragma unroll
    for (int n=0;n<8;n++) acc[q][n] = (f32x4){0.f,0.f,0.f,0.f};

  bf16x8 a0[4], a1[4], bP[4], bQ[4];

#define ABASE(S) ((S)*16384)
#define BBASE(S) (32768 + (S)*16384)

#define RD_A(buf, S, kc) do{ \
    const unsigned short* L_ = lds + ABASE(S) + (aB ^ ((kc)?32:0)); \
    buf[0] = *(const bf16x8*)(L_); \
    buf[1] = *(const bf16x8*)(L_ + 1024); \
    buf[2] = *(const bf16x8*)(L_ + 2048); \
    buf[3] = *(const bf16x8*)(L_ + 3072); }while(0)

#define RD_B(buf, S, h, kc) do{ \
    const unsigned short* L_ = lds + BBASE(S) + (h)*4096 + (bB ^ ((kc)?32:0)); \
    buf[0] = *(const bf16x8*)(L_); \
    buf[1] = *(const bf16x8*)(L_ + 1024); \
    buf[2] = *(const bf16x8*)(L_ + 2048); \
    buf[3] = *(const bf16x8*)(L_ + 3072); }while(0)

#define STG(p, DB, OFF) GL16((p) + (OFF), lds + (DB) + wid*512)

#define MMX(AF, BF, NB) do{ \
    _Pragma("unroll") for (int q=0;q<4;q++) \
      _Pragma("unroll") for (int nn=0;nn<4;nn++) \
        acc[q][(NB)+nn] = __builtin_amdgcn_mfma_f32_16x16x32_bf16( \
            AF[q], BF[nn], acc[q][(NB)+nn], 0, 0, 0); }while(0)

#define LGKM0 asm volatile("s_waitcnt lgkmcnt(0)" ::: "memory")
#define BAR  __builtin_amdgcn_s_barrier()
#define VM0  asm volatile("s_waitcnt vmcnt(0)" ::: "memory")
#define VNOP do{}while(0)

#define TILE(S, OB1, SP, V4) do{ \
    if (SP){ \
      STG(pA0, ABASE((S)^1) + 0,     OB1); \
      STG(pA1, ABASE((S)^1) + 4096,  OB1); \
      STG(pA2, ABASE((S)^1) + 8192,  OB1); \
      STG(pA3, ABASE((S)^1) + 12288, OB1); \
      STG(pB0, BBASE((S)^1) + 0,     OB1); \
      STG(pB1, BBASE((S)^1) + 4096,  OB1); \
      STG(pB2, BBASE((S)^1) + 8192,  OB1); \
      STG(pB3, BBASE((S)^1) + 12288, OB1); } \
    RD_A(a0, S, 0); RD_B(bP, S, 0, 0); RD_B(bQ, S, 1, 0); \
    MMX(a0, bP, 0); \
    RD_A(a1, S, 1); RD_B(bP, S, 1, 1); \
    MMX(a0, bQ, 4); \
    RD_B(bQ, S, 0, 1); \
    MMX(a1, bP, 4); \
    MMX(a1, bQ, 0); \
    LGKM0; V4; BAR; \
    asm volatile("" ::: "memory"); \
  }while(0)

  int nk = K >> 6;                          // 24 K-tiles
  STG(pA0, ABASE(0)+0, 0);     STG(pA1, ABASE(0)+4096, 0);
  STG(pA2, ABASE(0)+8192, 0);  STG(pA3, ABASE(0)+12288, 0);
  STG(pB0, BBASE(0)+0, 0);     STG(pB1, BBASE(0)+4096, 0);
  STG(pB2, BBASE(0)+8192, 0);  STG(pB3, BBASE(0)+12288, 0);
  VM0; BAR;
  asm volatile("" ::: "memory");

  for (int tt = 0; tt < (nk-2)/2; ++tt){
    TILE(0,  64, 1, VM0);
    TILE(1, 128, 1, VM0);
    pA0 += 128; pA1 += 128; pA2 += 128; pA3 += 128;
    pB0 += 128; pB1 += 128; pB2 += 128; pB3 += 128;
  }
  TILE(0, 64, 1, VM0);
  TILE(1, 0, 0, VNOP);

#undef TILE
#undef RD_A
#undef RD_B
#undef STG
#undef MMX

  int colb = bcol + wc*128 + fr;
  float bv[8];
  #pragma unroll
  for (int n=0;n<8;n++) bv[n] = bias[colb + n*16];
  int r0 = brow + wr*64 + (lane>>4)*4;
  #pragma unroll
  for (int q=0;q<4;q++){
    #pragma unroll
    for (int j=0;j<4;j++){
      int r = r0 + q*16 + j;
      #pragma unroll
      for (int n=0;n<8;n++){
        float x = acc[q][n][j] + bv[n];
        x = x / (1.0f + expf(-x));
        C[(size_t)r*N + colb + n*16] = f2bf(x);
      }
    }
  }
}

// ---------------------------------------------------------------------------
// GEMM2: 64x64 tile, 256 threads (4 waves 2x2, wave-tile 32x32), BK=64,
// R7-style 2-slot double-buffer: stage tile T+1 during compute of tile T,
// one lgkmcnt(0)+vmcnt(0)+barrier per K-tile (was: 2 syncthreads + in-tile
// stage drain).  32 KB LDS -> 4+ blocks/CU; grid 1024 = 4 blocks/CU.
// Swizzle: granule g of row r stored at g ^ (r&7) (same as gemm1).
// A [M][K] bf16, Bt [N][K] bf16, C = A@Bt^T + bias as f32 [M][N].
__global__ __launch_bounds__(256) void gemm2_db_kernel(
  const unsigned short* __restrict__ A, const unsigned short* __restrict__ Bt,
  const float* __restrict__ bias, float* __restrict__ C,
  int M, int N, int K)
{
  __shared__ unsigned short lds2[16384];  // A: slot s at s*4096; B at 8192+s*4096
  int nbx = N >> 6;
  int bid = blockIdx.x;
  if ((gridDim.x & 7) == 0){
    int chunk = gridDim.x >> 3;
    bid = (bid & 7)*chunk + (bid >> 3);
  }
  int bx = bid % nbx, by = bid / nbx;
  int brow = by*64, bcol = bx*64;
  int tid = threadIdx.x, lane = tid & 63, wid = tid >> 6;
  int wr = wid >> 1, wc = wid & 1;

  int srow = tid >> 3;                      // 0..31
  int sg   = ((tid & 7) ^ (srow & 7)) << 3;
  const unsigned short* pA0 = A  + (size_t)(brow + srow)*K + sg;
  const unsigned short* pA1 = pA0 + (size_t)32*K;
  const unsigned short* pB0 = Bt + (size_t)(bcol + srow)*K + sg;
  const unsigned short* pB1 = pB0 + (size_t)32*K;

  int fr = lane & 15, kb = lane >> 4;
  int g0 = (kb ^ (fr & 7)) << 3;
  int aB = (wr*32 + fr)*64 + g0;
  int bB = (wc*32 + fr)*64 + g0;

  f32x4 acc[2][2];
  #pragma unroll
  for (int i=0;i<2;i++)
    #pragma unroll
    for (int j=0;j<2;j++) acc[i][j] = (f32x4){0.f,0.f,0.f,0.f};

#define STG2(S, OFF) do{ \
    GL16(pA0 + (OFF), lds2 + (S)*4096 + wid*512); \
    GL16(pA1 + (OFF), lds2 + (S)*4096 + 2048 + wid*512); \
    GL16(pB0 + (OFF), lds2 + 8192 + (S)*4096 + wid*512); \
    GL16(pB1 + (OFF), lds2 + 8192 + (S)*4096 + 2048 + wid*512); }while(0)

  STG2(0, 0);
  asm volatile("s_waitcnt vmcnt(0)" ::: "memory");
  __builtin_amdgcn_s_barrier();
  asm volatile("" ::: "memory");

  int nt = K >> 6;                          // 16 K-tiles
  for (int t2 = 0; t2 < nt; ++t2){
    int S = t2 & 1;
    if (t2 < nt-1) STG2(S^1, (t2+1)*64);
    bf16x8 a[2][2], b[2][2];
    #pragma unroll
    for (int m=0;m<2;m++)
      #pragma unroll
      for (int kc=0;kc<2;kc++){
        a[m][kc] = *(const bf16x8*)(lds2 + (S)*4096 + ((aB + m*1024) ^ (kc<<5)));
        b[m][kc] = *(const bf16x8*)(lds2 + 8192 + (S)*4096 + ((bB + m*1024) ^ (kc<<5)));
      }
    #pragma unroll
    for (int kc=0;kc<2;kc++)
      #pragma unroll
      for (int m=0;m<2;m++)
        #pragma unroll
        for (int n=0;n<2;n++)
          acc[m][n] = __builtin_amdgcn_mfma_f32_16x16x32_bf16(a[m][kc], b[n][kc], acc[m][n], 0, 0, 0);
    asm volatile("s_waitcnt lgkmcnt(0)" ::: "memory");
    asm volatile("s_waitcnt vmcnt(0)" ::: "memory");
    __builtin_amdgcn_s_barrier();
    asm volatile("" ::: "memory");
  }
#undef STG2

  int col0 = bcol + wc*32 + fr;
  int row0 = brow + wr*32 + (lane >> 4)*4;
  #pragma unroll
  for (int m=0;m<2;m++){
    #pragma unroll
    for (int j=0;j<4;j++){
      int r = row0 + m*16 + j;
      #pragma unroll
      for (int n=0;n<2;n++){
        int c = col0 + n*16;
        C[(size_t)r*N + c] = acc[m][n][j] + bias[c];
      }
    }
  }
}

// ---------------------------------------------------------------------------
// Final output: right-aligned pieces + pos_emb, zeros elsewhere, plus mask plane.
__global__ __launch_bounds__(256) void output_kernel(
  const float* __restrict__ ev, const float* __restrict__ pos_emb,
  const float* __restrict__ sep_token,
  const int* __restrict__ src, const int* __restrict__ count,
  float* __restrict__ out)
{
  int tid  = threadIdx.x;
  int tpos = blockIdx.x*4 + (tid>>6);
  int lane = tid & 63;
  int b = tpos >> 10;
  int t = tpos & 1023;
  int cnt = count[b];
  int start = Mm_ - cnt;
  float4 val = make_float4(0.f,0.f,0.f,0.f);
  float maskv = 0.f;
  if (t >= start){
    maskv = 1.f;
    int slot = src[b*Mm_ + (t - start)];
    const float* sv = (slot & 1) ? sep_token
                                 : ev + (size_t)(b*Ll_ + (slot>>1))*Hh;
    float4 x = *(const float4*)(sv + lane*4);
    float4 p = *(const float4*)(pos_emb + (size_t)t*Hh + lane*4);
    val = make_float4(x.x+p.x, x.y+p.y, x.z+p.z, x.w+p.w);
  }
  *(float4*)(out + (size_t)tpos*Hh + lane*4) = val;
  if (lane==0) out[(size_t)Bb_*Mm_*Hh + tpos] = maskv;
}

// ---------------------------------------------------------------------------
extern "C" void kernel_launch(void* const* d_in, const int* in_sizes, int n_in,
                              void* d_out, int out_size, void* d_ws, size_t ws_size,
                              hipStream_t stream) {
  const int* tok    = (const int*)d_in[0];
  const int* post   = (const int*)d_in[1];
  const int* auth   = (const int*)d_in[2];
  const int* act    = (const int*)d_in[3];
  const int* tg     = (const int*)d_in[4];
  const int* gid    = (const int*)d_in[5];
  const void* maskp =             d_in[6];
  const float* token_emb = (const float*)d_in[7];
  const float* time_emb  = (const float*)d_in[8];
  const float* group_emb = (const float*)d_in[9];
  const float* pos_emb   = (const float*)d_in[10];
  const float* sep_token = (const float*)d_in[11];
  const float* ln_g = (const float*)d_in[12];
  const float* ln_b = (const float*)d_in[13];
  const float* W1   = (const float*)d_in[14];
  const float* b1   = (const float*)d_in[15];
  const float* W2   = (const float*)d_in[16];
  const float* b2   = (const float*)d_in[17];

  char* ws = (char*)d_ws;
  size_t off = 0;
  int* flag = (int*)ws;                                  off += 256;  // reserved
  unsigned short* xn  = (unsigned short*)(ws + off);     off += (size_t)BL_*SIXH*2;
  unsigned short* h1  = (unsigned short*)(ws + off);     off += (size_t)BL_*N1_*2;
  float*          ev  = (float*)(ws + off);              off += (size_t)BL_*N2_*4;
  unsigned short* w1t = (unsigned short*)(ws + off);     off += (size_t)K1_*N1_*2;
  unsigned short* w2t = (unsigned short*)(ws + off);     off += (size_t)K2_*N2_*2;
  int*            src = (int*)(ws + off);                off += (size_t)Bb_*Mm_*4;
  int*            cnt = (int*)(ws + off);                off += 256;
  (void)flag;

  const int PRE_BLOCKS = 32 + 896 + BL_/4;   // merge + transpose + gather = 5024
  fused_pre_kernel<<<PRE_BLOCKS,512,0,stream>>>(
      tok,post,auth,act,tg,gid, maskp,
      token_emb,time_emb,group_emb, ln_g,ln_b,
      W1,w1t,W2,w2t, xn, src,cnt);
  gemm1_cs_kernel<<<(BL_/256)*(N1_/256),512,0,stream>>>(
      xn, w1t, b1, h1, BL_, N1_, K1_);
  gemm2_db_kernel<<<(BL_/64)*(N2_/64),256,0,stream>>>(
      h1, w2t, b2, ev, BL_, N2_, K2_);
  output_kernel<<<(Bb_*Mm_)/4,256,0,stream>>>(ev, pos_emb, sep_token, src, cnt, (float*)d_out);
}